// Round 1
// baseline (677.466 us; speedup 1.0000x reference)
//
#include <hip/hip_runtime.h>

typedef unsigned short u16;
typedef unsigned int u32;

typedef __attribute__((ext_vector_type(8))) short short8;   // 8 bf16 = 4 VGPRs
typedef __attribute__((ext_vector_type(4))) float floatx4;  // MFMA accumulator

__device__ __forceinline__ float b2f(u16 h) {
  u32 u = ((u32)h) << 16;
  return __builtin_bit_cast(float, u);
}
__device__ __forceinline__ u16 f2b(float f) {
  u32 u = __builtin_bit_cast(u32, f);
  u32 r = 0x7FFFu + ((u >> 16) & 1u);  // RNE
  return (u16)((u + r) >> 16);
}

#define BM 128
#define BN 128
#define BK 32
#define LDK 40  // BK + 8 pad: row stride 80B = 20 banks -> 2-way max (free)

enum { EPI_PHI_BIAS = 0, EPI_BIAS = 1, EPI_NONE = 2, EPI_ZSCALE = 3, EPI_BIAS_F32 = 4 };

// C[m,n] = sum_k A[m,k] * B[n,k]   (both operands K-contiguous, "gemm_bt")
// TRANS_OUT: write C transposed as [4][N][4096] (per-batch token split of M=16384)
template<int EPI, bool A_F32, bool TRANS_OUT>
__global__ __launch_bounds__(256)
void gemm_bt(const void* __restrict__ Aall, const u16* __restrict__ Ball,
             const float* __restrict__ bias, const float* __restrict__ Zall,
             void* __restrict__ Call,
             int M, int N, int K, int ldA, int ldB, int ldC,
             long sAb, long sBb, long sCb, long sZb)
{
  __shared__ char smem[TRANS_OUT ? (BN * (BM + 8) * 2) : (2 * BM * LDK * 2)];
  u16* sA = (u16*)smem;
  u16* sB = sA + BM * LDK;

  const int tid = threadIdx.x;
  const int lane = tid & 63;
  const int wave = tid >> 6;
  const int wm = wave >> 1, wn = wave & 1;       // 2x2 waves, 64x64 each
  const int fl = lane & 15;
  const int q8 = (lane >> 4) * 8;
  const int r4 = (lane >> 4) * 4;
  const int bm0 = blockIdx.x * BM, bn0 = blockIdx.y * BN;
  const int bz = blockIdx.z;

  const float* Af = (const float*)Aall + (size_t)bz * sAb;
  const u16*   Ah = (const u16*)Aall + (size_t)bz * sAb;
  const u16*   Bp = Ball + (size_t)bz * sBb;

  floatx4 zero = {0.f, 0.f, 0.f, 0.f};
  floatx4 acc[4][4];
  #pragma unroll
  for (int i = 0; i < 4; ++i)
    #pragma unroll
    for (int j = 0; j < 4; ++j) acc[i][j] = zero;

  for (int k0 = 0; k0 < K; k0 += BK) {
    __syncthreads();
    if constexpr (A_F32) {
      #pragma unroll
      for (int i = 0; i < 4; ++i) {
        int e = tid + i * 256;              // 128x32 fp32 = 1024 float4
        int row = e >> 3, c = (e & 7) * 4;
        float4 vv = *(const float4*)(Af + (size_t)(bm0 + row) * ldA + k0 + c);
        ushort4 h;
        h.x = f2b(vv.x); h.y = f2b(vv.y); h.z = f2b(vv.z); h.w = f2b(vv.w);
        *(ushort4*)(sA + row * LDK + c) = h;
      }
    } else {
      #pragma unroll
      for (int i = 0; i < 2; ++i) {
        int e = tid + i * 256;              // 128x32 bf16 = 512 x 16B
        int row = e >> 2, c = (e & 3) * 8;
        *(int4*)(sA + row * LDK + c) =
            *(const int4*)(Ah + (size_t)(bm0 + row) * ldA + k0 + c);
      }
    }
    #pragma unroll
    for (int i = 0; i < 2; ++i) {
      int e = tid + i * 256;
      int row = e >> 2, c = (e & 3) * 8;
      *(int4*)(sB + row * LDK + c) =
          *(const int4*)(Bp + (size_t)(bn0 + row) * ldB + k0 + c);
    }
    __syncthreads();

    short8 aF[4], bF[4];
    #pragma unroll
    for (int mi = 0; mi < 4; ++mi)
      aF[mi] = *(const short8*)(sA + (wm * 64 + mi * 16 + fl) * LDK + q8);
    #pragma unroll
    for (int ni = 0; ni < 4; ++ni)
      bF[ni] = *(const short8*)(sB + (wn * 64 + ni * 16 + fl) * LDK + q8);
    #pragma unroll
    for (int mi = 0; mi < 4; ++mi)
      #pragma unroll
      for (int ni = 0; ni < 4; ++ni)
        acc[mi][ni] = __builtin_amdgcn_mfma_f32_16x16x32_bf16(aF[mi], bF[ni], acc[mi][ni], 0, 0, 0);
  }

  if constexpr (!TRANS_OUT) {
    #pragma unroll
    for (int mi = 0; mi < 4; ++mi) {
      #pragma unroll
      for (int ni = 0; ni < 4; ++ni) {
        int col = bn0 + wn * 64 + ni * 16 + fl;
        #pragma unroll
        for (int r = 0; r < 4; ++r) {
          int row = bm0 + wm * 64 + mi * 16 + r4 + r;
          float vv = acc[mi][ni][r];
          if constexpr (EPI == EPI_PHI_BIAS) { vv += bias[col]; vv = __expf(-0.5f * vv * vv); }
          if constexpr (EPI == EPI_BIAS || EPI == EPI_BIAS_F32) vv += bias[col];
          if constexpr (EPI == EPI_ZSCALE) vv *= Zall[(size_t)bz * sZb + row];
          if constexpr (EPI == EPI_BIAS_F32)
            ((float*)Call)[(size_t)bz * sCb + (size_t)row * ldC + col] = vv;
          else
            ((u16*)Call)[(size_t)bz * sCb + (size_t)row * ldC + col] = f2b(vv);
        }
      }
    }
  } else {
    // transpose tile through LDS, then coalesced 16B stores into [4][N][4096]
    __syncthreads();
    u16* sT = (u16*)smem;  // [BN][BM+8]
    #pragma unroll
    for (int mi = 0; mi < 4; ++mi) {
      #pragma unroll
      for (int ni = 0; ni < 4; ++ni) {
        int colL = wn * 64 + ni * 16 + fl;
        int row0 = wm * 64 + mi * 16 + r4;
        float bcol = bias[bn0 + colL];
        ushort4 h;
        #pragma unroll
        for (int r = 0; r < 4; ++r) {
          float vv = acc[mi][ni][r] + bcol;
          if constexpr (EPI == EPI_PHI_BIAS) vv = __expf(-0.5f * vv * vv);
          ((u16*)&h)[r] = f2b(vv);
        }
        *(ushort4*)(sT + colL * (BM + 8) + row0) = h;  // 4 consecutive t, one d
      }
    }
    __syncthreads();
    #pragma unroll
    for (int i = 0; i < 8; ++i) {
      int c = tid + i * 256;                // 2048 x 16B chunks
      int dloc = c >> 4, t8 = (c & 15) * 8;
      int4 vv = *(const int4*)(sT + dloc * (BM + 8) + t8);
      int gd = bn0 + dloc;
      int gt = bm0 + t8;
      int batch = gt >> 12, tt = gt & 4095;
      *(int4*)((u16*)Call + ((size_t)batch * N + gd) * 4096 + tt) = vv;
    }
  }
}

__global__ __launch_bounds__(256)
void wconv(const float* __restrict__ w0, const float* __restrict__ w1,
           const float* __restrict__ w2, const float* __restrict__ w3,
           u16* __restrict__ dst) {
  unsigned e = blockIdx.x * 256 + threadIdx.x;  // 1M threads, 4 elems each
  int mat = e >> 18;
  size_t off = (size_t)(e & 262143) * 4;
  const float* src = mat == 0 ? w0 : mat == 1 ? w1 : mat == 2 ? w2 : w3;
  float4 v = *(const float4*)(src + off);
  ushort4 h;
  h.x = f2b(v.x); h.y = f2b(v.y); h.z = f2b(v.z); h.w = f2b(v.w);
  *(ushort4*)(dst + (size_t)mat * 1048576 + off) = h;
}

// Ksum[b*1024+d] = sum_t KT[b][d][t]; one wave per (b,d) row
__global__ __launch_bounds__(256)
void ksum_rows(const u16* __restrict__ KT, float* __restrict__ Ksum) {
  int lane = threadIdx.x & 63;
  int row = blockIdx.x * 4 + (threadIdx.x >> 6);
  const u16* p = KT + (size_t)row * 4096;
  float s = 0.f;
  #pragma unroll
  for (int i = 0; i < 8; ++i) {
    int4 d = *(const int4*)(p + i * 512 + lane * 8);
    const u16* h = (const u16*)&d;
    #pragma unroll
    for (int j = 0; j < 8; ++j) s += b2f(h[j]);
  }
  #pragma unroll
  for (int off = 32; off; off >>= 1) s += __shfl_xor(s, off, 64);
  if (lane == 0) Ksum[row] = s;
}

// Z[t] = 1/(Q[t,:]·Ksum[batch,:] + 1e-6); one wave per token
__global__ __launch_bounds__(256)
void zden(const u16* __restrict__ Qb, const float* __restrict__ Ksum,
          float* __restrict__ Z) {
  int lane = threadIdx.x & 63;
  int t = blockIdx.x * 4 + (threadIdx.x >> 6);
  const u16* qp = Qb + (size_t)t * 1024;
  const float* ks = Ksum + (size_t)(t >> 12) * 1024;
  float s = 0.f;
  #pragma unroll
  for (int i = 0; i < 2; ++i) {
    int idx = i * 512 + lane * 8;
    int4 d = *(const int4*)(qp + idx);
    const u16* h = (const u16*)&d;
    float4 k0 = *(const float4*)(ks + idx);
    float4 k1 = *(const float4*)(ks + idx + 4);
    s += b2f(h[0]) * k0.x + b2f(h[1]) * k0.y + b2f(h[2]) * k0.z + b2f(h[3]) * k0.w
       + b2f(h[4]) * k1.x + b2f(h[5]) * k1.y + b2f(h[6]) * k1.z + b2f(h[7]) * k1.w;
  }
  #pragma unroll
  for (int off = 32; off; off >>= 1) s += __shfl_xor(s, off, 64);
  if (lane == 0) Z[t] = 1.0f / (s + 1e-6f);
}

extern "C" void kernel_launch(void* const* d_in, const int* in_sizes, int n_in,
                              void* d_out, int out_size, void* d_ws, size_t ws_size,
                              hipStream_t stream) {
  const float* q  = (const float*)d_in[0];
  const float* k  = (const float*)d_in[1];
  const float* v  = (const float*)d_in[2];
  const float* Wq = (const float*)d_in[3];
  const float* bq = (const float*)d_in[4];
  const float* Wk = (const float*)d_in[5];
  const float* bk = (const float*)d_in[6];
  const float* Wv = (const float*)d_in[7];
  const float* bv = (const float*)d_in[8];
  const float* Wo = (const float*)d_in[9];
  const float* bo = (const float*)d_in[10];
  float* out = (float*)d_out;

  // workspace layout (~112.1 MiB)
  u16* Wqb = (u16*)d_ws;                 // 4x 1024x1024 bf16 = 8 MiB
  u16* Wkb = Wqb + 1048576;
  u16* Wvb = Wkb + 1048576;
  u16* Wob = Wvb + 1048576;
  u16* Qb  = Wob + 1048576;              // [16384][1024] bf16, 32 MiB
  u16* KT  = Qb  + 16777216;             // [4][1024][4096] bf16, 32 MiB
  u16* VT  = KT  + 16777216;             // [4][1024][4096] bf16, 32 MiB
  u16* KVT = VT  + 16777216;             // [4][1024][1024] bf16, 8 MiB
  float* Ksum = (float*)(KVT + 4194304); // [4][1024] f32
  float* Z    = Ksum + 4096;             // [16384] f32
  u16* Y = KT;                           // alias: KT dead after S2, Y born in S3

  wconv<<<4096, 256, 0, stream>>>(Wq, Wk, Wv, Wo, Wqb);

  // S1: projections (A fp32). Q normal layout; K,V transposed layout.
  dim3 g1(128, 8, 1);
  gemm_bt<EPI_PHI_BIAS, true, false><<<g1, 256, 0, stream>>>(
      q, Wqb, bq, nullptr, Qb, 16384, 1024, 1024, 1024, 1024, 1024, 0, 0, 0, 0);
  gemm_bt<EPI_PHI_BIAS, true, true><<<g1, 256, 0, stream>>>(
      k, Wkb, bk, nullptr, KT, 16384, 1024, 1024, 1024, 1024, 0, 0, 0, 0, 0);
  gemm_bt<EPI_BIAS, true, true><<<g1, 256, 0, stream>>>(
      v, Wvb, bv, nullptr, VT, 16384, 1024, 1024, 1024, 1024, 0, 0, 0, 0, 0);

  ksum_rows<<<1024, 256, 0, stream>>>(KT, Ksum);
  zden<<<4096, 256, 0, stream>>>(Qb, Ksum, Z);

  // S2: KVT[l,d] = sum_t VT[l,t] * KT[d,t]  (per batch)
  dim3 g2(8, 8, 4);
  gemm_bt<EPI_NONE, false, false><<<g2, 256, 0, stream>>>(
      VT, KT, nullptr, nullptr, KVT, 1024, 1024, 4096, 4096, 4096, 1024,
      4194304L, 4194304L, 1048576L, 0);

  // S3: Y[t,l] = (sum_d Qb[t,d] * KVT[l,d]) * Z[t]  (per batch)
  dim3 g3(32, 8, 4);
  gemm_bt<EPI_ZSCALE, false, false><<<g3, 256, 0, stream>>>(
      Qb, KVT, nullptr, Z, Y, 4096, 1024, 1024, 1024, 1024, 1024,
      4194304L, 1048576L, 4194304L, 4096L);

  // S4: out[t,n] = sum_l Y[t,l] * Wo[n,l] + bo[n]  (fp32 out)
  dim3 g4(128, 8, 1);
  gemm_bt<EPI_BIAS_F32, false, false><<<g4, 256, 0, stream>>>(
      Y, Wob, bo, nullptr, out, 16384, 1024, 1024, 1024, 1024, 1024, 0, 0, 0, 0);
}

// Round 2
// 631.077 us; speedup vs baseline: 1.0735x; 1.0735x over previous
//
#include <hip/hip_runtime.h>

typedef unsigned short u16;
typedef unsigned int u32;
typedef unsigned long long u64;

typedef __attribute__((ext_vector_type(8))) short short8;   // 8 bf16 = 4 VGPRs
typedef __attribute__((ext_vector_type(4))) float floatx4;  // MFMA accumulator

__device__ __forceinline__ float b2f(u16 h) {
  u32 u = ((u32)h) << 16;
  return __builtin_bit_cast(float, u);
}
__device__ __forceinline__ u16 f2b(float f) {
  u32 u = __builtin_bit_cast(u32, f);
  u32 r = 0x7FFFu + ((u >> 16) & 1u);  // RNE
  return (u16)((u + r) >> 16);
}

// async global->LDS, 16B per lane. LDS dest = wave-uniform base + lane*16.
__device__ __forceinline__ void gl_lds16(const void* g, void* l) {
  __builtin_amdgcn_global_load_lds(
      (__attribute__((address_space(1))) void*)(u64)g,
      (__attribute__((address_space(3))) void*)(u32)(u64)l, 16, 0, 0);
}

enum { EPI_PHI_BIAS = 0, EPI_BIAS = 1, EPI_NONE = 2, EPI_ZSCALE = 3, EPI_BIAS_F32 = 4 };

// C[m,n] = sum_k A[m,k] * B[n,k]  (both K-contiguous). 128x128x32 tile, 4 waves.
// bf16 tiles stored in LDS with superrow XOR swizzle: for (row r, 16B-chunk c):
//   R=r>>1, u=((r&1)<<2)|c, phys = R*8 + (u ^ (R&7))   -> fragment reads 2-way max
// fp32 A tile (S1): (row r, 16B-chunk c8 in 0..7): phys = r*8 + (c8 ^ (r&7))
template<int EPI, bool A_F32, bool TRANS_OUT>
__global__ __launch_bounds__(256)
void gemm_bt(const void* __restrict__ Aall, const u16* __restrict__ Ball,
             const float* __restrict__ bias, const float* __restrict__ Zall,
             void* __restrict__ Call,
             int M, int N, int K, int ldA, int ldB, int ldC,
             long sAb, long sBb, long sCb, long sZb)
{
  constexpr int ABYTES = A_F32 ? 16384 : 8192;
  constexpr int STAGE  = ABYTES + 8192;
  constexpr int SMEM   = (TRANS_OUT && 34816 > STAGE) ? 34816 : STAGE;
  __shared__ char smem[SMEM];
  char* sA = smem;
  char* sB = smem + ABYTES;

  const int tid  = threadIdx.x;
  const int lane = tid & 63;
  const int wave = tid >> 6;
  const int wm = wave >> 1, wn = wave & 1;   // 2x2 waves, 64x64 each
  const int fl = lane & 15;
  const int q  = lane >> 4;                  // K 16B-chunk index for fragments
  const int r4 = q * 4;
  const int bm0 = blockIdx.x * 128, bn0 = blockIdx.y * 128;
  const int bz = blockIdx.z;

  const float* Af = (const float*)Aall + (size_t)bz * sAb;
  const u16*   Ah = (const u16*)Aall + (size_t)bz * sAb;
  const u16*   Bp = Ball + (size_t)bz * sBb;

  // ---- staging address precompute (loop-invariant except +k0) ----
  const u16* gB[2]; void* lB[2];
  #pragma unroll
  for (int n = 0; n < 2; ++n) {
    int j = n * 256 + tid;                 // physical 16B slot in B tile
    int R = j >> 3, u = (j & 7) ^ (R & 7);
    int r = (R << 1) | (u >> 2), c = u & 3;
    gB[n] = Bp + (size_t)(bn0 + r) * ldB + c * 8;
    lB[n] = sB + (n * 256 + wave * 64) * 16;
  }
  const u16* gAh[2]; const float* gAf[4]; void* lA[4];
  if constexpr (A_F32) {
    #pragma unroll
    for (int n = 0; n < 4; ++n) {
      int j = n * 256 + tid;               // physical 16B slot in fp32 A tile
      int r = j >> 3, c8 = (j & 7) ^ (r & 7);
      gAf[n] = Af + (size_t)(bm0 + r) * ldA + c8 * 4;
      lA[n] = sA + (n * 256 + wave * 64) * 16;
    }
  } else {
    #pragma unroll
    for (int n = 0; n < 2; ++n) {
      int j = n * 256 + tid;
      int R = j >> 3, u = (j & 7) ^ (R & 7);
      int r = (R << 1) | (u >> 2), c = u & 3;
      gAh[n] = Ah + (size_t)(bm0 + r) * ldA + c * 8;
      lA[n] = sA + (n * 256 + wave * 64) * 16;
    }
  }

  // ---- fragment LDS byte offsets (constant across the whole K loop) ----
  int aoff[4], boff[4];
  #pragma unroll
  for (int i = 0; i < 4; ++i) {
    int rb = wn * 64 + i * 16 + fl;
    int Rb = rb >> 1, ub = ((((rb & 1) << 2) | q) ^ (Rb & 7));
    boff[i] = (Rb * 8 + ub) * 16;
    int ra = wm * 64 + i * 16 + fl;
    if constexpr (A_F32) {
      aoff[i] = (ra * 8 + ((2 * q) ^ (ra & 7))) * 16;   // low-half chunk; ^16 = high half
    } else {
      int Ra = ra >> 1, ua = ((((ra & 1) << 2) | q) ^ (Ra & 7));
      aoff[i] = (Ra * 8 + ua) * 16;
    }
  }

  floatx4 zero = {0.f, 0.f, 0.f, 0.f};
  floatx4 acc[4][4];
  #pragma unroll
  for (int i = 0; i < 4; ++i)
    #pragma unroll
    for (int j = 0; j < 4; ++j) acc[i][j] = zero;

  for (int k0 = 0; k0 < K; k0 += 32) {
    __syncthreads();                      // previous iter's LDS reads done
    if constexpr (A_F32) {
      #pragma unroll
      for (int n = 0; n < 4; ++n) gl_lds16(gAf[n] + k0, lA[n]);
    } else {
      #pragma unroll
      for (int n = 0; n < 2; ++n) gl_lds16(gAh[n] + k0, lA[n]);
    }
    #pragma unroll
    for (int n = 0; n < 2; ++n) gl_lds16(gB[n] + k0, lB[n]);
    __syncthreads();                      // drains vmcnt (global_load_lds)

    short8 aF[4], bF[4];
    if constexpr (A_F32) {
      #pragma unroll
      for (int i = 0; i < 4; ++i) {
        float4 x = *(const float4*)(sA + aoff[i]);          // k = q8..q8+3
        float4 y = *(const float4*)(sA + (aoff[i] ^ 16));   // k = q8+4..q8+7
        const u32* xb = (const u32*)&x;
        const u32* yb = (const u32*)&y;
        union { u32 w[4]; short8 s; } cv;
        cv.w[0] = __builtin_amdgcn_perm(xb[1], xb[0], 0x07060302u);  // trunc pack
        cv.w[1] = __builtin_amdgcn_perm(xb[3], xb[2], 0x07060302u);
        cv.w[2] = __builtin_amdgcn_perm(yb[1], yb[0], 0x07060302u);
        cv.w[3] = __builtin_amdgcn_perm(yb[3], yb[2], 0x07060302u);
        aF[i] = cv.s;
      }
    } else {
      #pragma unroll
      for (int i = 0; i < 4; ++i) aF[i] = *(const short8*)(sA + aoff[i]);
    }
    #pragma unroll
    for (int i = 0; i < 4; ++i) bF[i] = *(const short8*)(sB + boff[i]);

    #pragma unroll
    for (int mi = 0; mi < 4; ++mi)
      #pragma unroll
      for (int ni = 0; ni < 4; ++ni)
        acc[mi][ni] = __builtin_amdgcn_mfma_f32_16x16x32_bf16(aF[mi], bF[ni], acc[mi][ni], 0, 0, 0);
  }

  if constexpr (!TRANS_OUT) {
    #pragma unroll
    for (int mi = 0; mi < 4; ++mi) {
      #pragma unroll
      for (int ni = 0; ni < 4; ++ni) {
        int col = bn0 + wn * 64 + ni * 16 + fl;
        #pragma unroll
        for (int r = 0; r < 4; ++r) {
          int row = bm0 + wm * 64 + mi * 16 + r4 + r;
          float vv = acc[mi][ni][r];
          if constexpr (EPI == EPI_PHI_BIAS) { vv += bias[col]; vv = __expf(-0.5f * vv * vv); }
          if constexpr (EPI == EPI_BIAS || EPI == EPI_BIAS_F32) vv += bias[col];
          if constexpr (EPI == EPI_ZSCALE) vv *= Zall[(size_t)bz * sZb + row];
          if constexpr (EPI == EPI_BIAS_F32)
            ((float*)Call)[(size_t)bz * sCb + (size_t)row * ldC + col] = vv;
          else
            ((u16*)Call)[(size_t)bz * sCb + (size_t)row * ldC + col] = f2b(vv);
        }
      }
    }
  } else {
    // transpose tile through LDS, then coalesced 16B stores into [4][N][4096]
    __syncthreads();
    u16* sT = (u16*)smem;  // [128][136]
    #pragma unroll
    for (int mi = 0; mi < 4; ++mi) {
      #pragma unroll
      for (int ni = 0; ni < 4; ++ni) {
        int colL = wn * 64 + ni * 16 + fl;
        int row0 = wm * 64 + mi * 16 + r4;
        float bcol = bias[bn0 + colL];
        ushort4 h;
        #pragma unroll
        for (int r = 0; r < 4; ++r) {
          float vv = acc[mi][ni][r] + bcol;
          if constexpr (EPI == EPI_PHI_BIAS) vv = __expf(-0.5f * vv * vv);
          ((u16*)&h)[r] = f2b(vv);
        }
        *(ushort4*)(sT + colL * 136 + row0) = h;  // 4 consecutive t, one d
      }
    }
    __syncthreads();
    #pragma unroll
    for (int i = 0; i < 8; ++i) {
      int c = tid + i * 256;                // 2048 x 16B chunks
      int dloc = c >> 4, t8 = (c & 15) * 8;
      int4 vv = *(const int4*)(sT + dloc * 136 + t8);
      int gd = bn0 + dloc;
      int gt = bm0 + t8;
      int batch = gt >> 12, tt = gt & 4095;
      *(int4*)((u16*)Call + ((size_t)batch * N + gd) * 4096 + tt) = vv;
    }
  }
}

__global__ __launch_bounds__(256)
void wconv(const float* __restrict__ w0, const float* __restrict__ w1,
           const float* __restrict__ w2, const float* __restrict__ w3,
           u16* __restrict__ dst) {
  unsigned e = blockIdx.x * 256 + threadIdx.x;
  int mat = e >> 18;
  size_t off = (size_t)(e & 262143) * 4;
  const float* src = mat == 0 ? w0 : mat == 1 ? w1 : mat == 2 ? w2 : w3;
  float4 v = *(const float4*)(src + off);
  ushort4 h;
  h.x = f2b(v.x); h.y = f2b(v.y); h.z = f2b(v.z); h.w = f2b(v.w);
  *(ushort4*)(dst + (size_t)mat * 1048576 + off) = h;
}

// Ksum[b*1024+d] = sum_t KT[b][d][t]; one wave per (b,d) row
__global__ __launch_bounds__(256)
void ksum_rows(const u16* __restrict__ KT, float* __restrict__ Ksum) {
  int lane = threadIdx.x & 63;
  int row = blockIdx.x * 4 + (threadIdx.x >> 6);
  const u16* p = KT + (size_t)row * 4096;
  float s = 0.f;
  #pragma unroll
  for (int i = 0; i < 8; ++i) {
    int4 d = *(const int4*)(p + i * 512 + lane * 8);
    const u16* h = (const u16*)&d;
    #pragma unroll
    for (int j = 0; j < 8; ++j) s += b2f(h[j]);
  }
  #pragma unroll
  for (int off = 32; off; off >>= 1) s += __shfl_xor(s, off, 64);
  if (lane == 0) Ksum[row] = s;
}

// Z[t] = 1/(Q[t,:]·Ksum[batch,:] + 1e-6); one wave per token
__global__ __launch_bounds__(256)
void zden(const u16* __restrict__ Qb, const float* __restrict__ Ksum,
          float* __restrict__ Z) {
  int lane = threadIdx.x & 63;
  int t = blockIdx.x * 4 + (threadIdx.x >> 6);
  const u16* qp = Qb + (size_t)t * 1024;
  const float* ks = Ksum + (size_t)(t >> 12) * 1024;
  float s = 0.f;
  #pragma unroll
  for (int i = 0; i < 2; ++i) {
    int idx = i * 512 + lane * 8;
    int4 d = *(const int4*)(qp + idx);
    const u16* h = (const u16*)&d;
    float4 k0 = *(const float4*)(ks + idx);
    float4 k1 = *(const float4*)(ks + idx + 4);
    s += b2f(h[0]) * k0.x + b2f(h[1]) * k0.y + b2f(h[2]) * k0.z + b2f(h[3]) * k0.w
       + b2f(h[4]) * k1.x + b2f(h[5]) * k1.y + b2f(h[6]) * k1.z + b2f(h[7]) * k1.w;
  }
  #pragma unroll
  for (int off = 32; off; off >>= 1) s += __shfl_xor(s, off, 64);
  if (lane == 0) Z[t] = 1.0f / (s + 1e-6f);
}

extern "C" void kernel_launch(void* const* d_in, const int* in_sizes, int n_in,
                              void* d_out, int out_size, void* d_ws, size_t ws_size,
                              hipStream_t stream) {
  const float* q  = (const float*)d_in[0];
  const float* k  = (const float*)d_in[1];
  const float* v  = (const float*)d_in[2];
  const float* Wq = (const float*)d_in[3];
  const float* bq = (const float*)d_in[4];
  const float* Wk = (const float*)d_in[5];
  const float* bk = (const float*)d_in[6];
  const float* Wv = (const float*)d_in[7];
  const float* bv = (const float*)d_in[8];
  const float* Wo = (const float*)d_in[9];
  const float* bo = (const float*)d_in[10];
  float* out = (float*)d_out;

  // workspace layout (~112.1 MiB)
  u16* Wqb = (u16*)d_ws;                 // 4x 1024x1024 bf16 = 8 MiB
  u16* Wkb = Wqb + 1048576;
  u16* Wvb = Wkb + 1048576;
  u16* Wob = Wvb + 1048576;
  u16* Qb  = Wob + 1048576;              // [16384][1024] bf16, 32 MiB
  u16* KT  = Qb  + 16777216;             // [4][1024][4096] bf16, 32 MiB
  u16* VT  = KT  + 16777216;             // [4][1024][4096] bf16, 32 MiB
  u16* KVT = VT  + 16777216;             // [4][1024][1024] bf16, 8 MiB
  float* Ksum = (float*)(KVT + 4194304); // [4][1024] f32
  float* Z    = Ksum + 4096;             // [16384] f32
  u16* Y = KT;                           // alias: KT dead after S2

  wconv<<<4096, 256, 0, stream>>>(Wq, Wk, Wv, Wo, Wqb);

  // S1: projections (A fp32, in-register trunc->bf16). K,V write transposed.
  dim3 g1(128, 8, 1);
  gemm_bt<EPI_PHI_BIAS, true, false><<<g1, 256, 0, stream>>>(
      q, Wqb, bq, nullptr, Qb, 16384, 1024, 1024, 1024, 1024, 1024, 0, 0, 0, 0);
  gemm_bt<EPI_PHI_BIAS, true, true><<<g1, 256, 0, stream>>>(
      k, Wkb, bk, nullptr, KT, 16384, 1024, 1024, 1024, 1024, 0, 0, 0, 0, 0);
  gemm_bt<EPI_BIAS, true, true><<<g1, 256, 0, stream>>>(
      v, Wvb, bv, nullptr, VT, 16384, 1024, 1024, 1024, 1024, 0, 0, 0, 0, 0);

  ksum_rows<<<1024, 256, 0, stream>>>(KT, Ksum);
  zden<<<4096, 256, 0, stream>>>(Qb, Ksum, Z);

  // S2: KVT[l,d] = sum_t VT[l,t] * KT[d,t]  (per batch)
  dim3 g2(8, 8, 4);
  gemm_bt<EPI_NONE, false, false><<<g2, 256, 0, stream>>>(
      VT, KT, nullptr, nullptr, KVT, 1024, 1024, 4096, 4096, 4096, 1024,
      4194304L, 4194304L, 1048576L, 0);

  // S3: Y[t,l] = (sum_d Qb[t,d] * KVT[l,d]) * Z[t]  (per batch)
  dim3 g3(32, 8, 4);
  gemm_bt<EPI_ZSCALE, false, false><<<g3, 256, 0, stream>>>(
      Qb, KVT, nullptr, Z, Y, 4096, 1024, 1024, 1024, 1024, 1024,
      4194304L, 1048576L, 4194304L, 4096L);

  // S4: out[t,n] = sum_l Y[t,l] * Wo[n,l] + bo[n]  (fp32 out)
  dim3 g4(128, 8, 1);
  gemm_bt<EPI_BIAS_F32, false, false><<<g4, 256, 0, stream>>>(
      Y, Wob, bo, nullptr, out, 16384, 1024, 1024, 1024, 1024, 1024, 0, 0, 0, 0);
}

// Round 3
// 578.621 us; speedup vs baseline: 1.1708x; 1.0907x over previous
//
#include <hip/hip_runtime.h>

typedef unsigned short u16;
typedef unsigned int u32;
typedef unsigned long long u64;

typedef __attribute__((ext_vector_type(8))) short short8;   // 8 bf16 = 4 VGPRs
typedef __attribute__((ext_vector_type(4))) float floatx4;  // MFMA accumulator

__device__ __forceinline__ float b2f(u16 h) {
  u32 u = ((u32)h) << 16;
  return __builtin_bit_cast(float, u);
}
__device__ __forceinline__ u16 f2b(float f) {
  u32 u = __builtin_bit_cast(u32, f);
  u32 r = 0x7FFFu + ((u >> 16) & 1u);  // RNE
  return (u16)((u + r) >> 16);
}

// async global->LDS, 16B per lane. LDS dest = wave-uniform base + lane*16.
__device__ __forceinline__ void gl_lds16(const void* g, void* l) {
  __builtin_amdgcn_global_load_lds(
      (__attribute__((address_space(1))) void*)(u64)g,
      (__attribute__((address_space(3))) void*)(u32)(u64)l, 16, 0, 0);
}

enum { EPI_PHI_BIAS = 0, EPI_BIAS = 1, EPI_NONE = 2, EPI_ZSCALE = 3, EPI_BIAS_F32 = 4 };

// C[m,n] = sum_k A[m,k] * B[n,k]  (both K-contiguous). 128x128x32 tile, 4 waves.
// Double-buffered LDS; prefetch for tile k+1 issued AFTER the barrier that
// drains tile k, so it overlaps tile k's ds_read+MFMA phase.
// bf16 tiles in LDS use superrow XOR swizzle (R=r>>1, u=((r&1)<<2)|c,
// phys=R*8+(u^(R&7))); fp32 A tile: phys=r*8+(c8^(r&7)). Fragment reads 2-way max.
// Split-K: blockIdx.z = kslice*(abmask+1)+batch; abz=bz&abmask picks A/B batch,
// kbase=(bz>>kshift)*K offsets the K-window; C tile at bz*sCb.
template<int EPI, bool A_F32, bool TRANS_OUT>
__global__ __launch_bounds__(256)
void gemm_bt(const void* __restrict__ Aall, const u16* __restrict__ Ball,
             const float* __restrict__ bias, const float* __restrict__ Zall,
             void* __restrict__ Call,
             int M, int N, int K, int ldA, int ldB, int ldC,
             long sAb, long sBb, long sCb, long sZb, int abmask, int kshift)
{
  constexpr int ABYTES = A_F32 ? 16384 : 8192;
  constexpr int STRIDE = ABYTES + 8192;           // one stage buffer (A+B)
  constexpr int SMEM   = (TRANS_OUT && 34816 > 2 * STRIDE) ? 34816 : 2 * STRIDE;
  __shared__ char smem[SMEM];

  const int tid  = threadIdx.x;
  const int lane = tid & 63;
  const int wave = tid >> 6;
  const int wm = wave >> 1, wn = wave & 1;   // 2x2 waves, 64x64 each
  const int fl = lane & 15;
  const int q  = lane >> 4;
  const int r4 = q * 4;
  const int bm0 = blockIdx.x * 128, bn0 = blockIdx.y * 128;
  const int bz = blockIdx.z;
  const int abz = bz & abmask;
  const int kbase = (bz >> kshift) * K;

  const float* Af = (const float*)Aall + (size_t)abz * sAb + kbase;
  const u16*   Ah = (const u16*)Aall + (size_t)abz * sAb + kbase;
  const u16*   Bp = Ball + (size_t)abz * sBb + kbase;

  // ---- staging addresses (global per-lane; LDS offsets wave-uniform) ----
  const u16* gB[2]; int bL[2];
  #pragma unroll
  for (int n = 0; n < 2; ++n) {
    int j = n * 256 + tid;                 // physical 16B slot in B tile
    int R = j >> 3, u = (j & 7) ^ (R & 7);
    int r = (R << 1) | (u >> 2), c = u & 3;
    gB[n] = Bp + (size_t)(bn0 + r) * ldB + c * 8;
    bL[n] = (n * 256 + wave * 64) * 16;
  }
  const u16* gAh[2]; const float* gAf[4]; int aL[4];
  if constexpr (A_F32) {
    #pragma unroll
    for (int n = 0; n < 4; ++n) {
      int j = n * 256 + tid;               // physical 16B slot in fp32 A tile
      int r = j >> 3, c8 = (j & 7) ^ (r & 7);
      gAf[n] = Af + (size_t)(bm0 + r) * ldA + c8 * 4;
      aL[n] = (n * 256 + wave * 64) * 16;
    }
  } else {
    #pragma unroll
    for (int n = 0; n < 2; ++n) {
      int j = n * 256 + tid;
      int R = j >> 3, u = (j & 7) ^ (R & 7);
      int r = (R << 1) | (u >> 2), c = u & 3;
      gAh[n] = Ah + (size_t)(bm0 + r) * ldA + c * 8;
      aL[n] = (n * 256 + wave * 64) * 16;
    }
  }

  // ---- fragment LDS byte offsets (within one stage buffer) ----
  int aoff[4], boff[4];
  #pragma unroll
  for (int i = 0; i < 4; ++i) {
    int rb = wn * 64 + i * 16 + fl;
    int Rb = rb >> 1, ub = ((((rb & 1) << 2) | q) ^ (Rb & 7));
    boff[i] = (Rb * 8 + ub) * 16;
    int ra = wm * 64 + i * 16 + fl;
    if constexpr (A_F32) {
      aoff[i] = (ra * 8 + ((2 * q) ^ (ra & 7))) * 16;   // low chunk; ^16 = high
    } else {
      int Ra = ra >> 1, ua = ((((ra & 1) << 2) | q) ^ (Ra & 7));
      aoff[i] = (Ra * 8 + ua) * 16;
    }
  }

  floatx4 zero = {0.f, 0.f, 0.f, 0.f};
  floatx4 acc[4][4];
  #pragma unroll
  for (int i = 0; i < 4; ++i)
    #pragma unroll
    for (int j = 0; j < 4; ++j) acc[i][j] = zero;

  auto stage = [&](int k0, char* base) {
    if constexpr (A_F32) {
      #pragma unroll
      for (int n = 0; n < 4; ++n) gl_lds16(gAf[n] + k0, base + aL[n]);
    } else {
      #pragma unroll
      for (int n = 0; n < 2; ++n) gl_lds16(gAh[n] + k0, base + aL[n]);
    }
    #pragma unroll
    for (int n = 0; n < 2; ++n) gl_lds16(gB[n] + k0, base + ABYTES + bL[n]);
  };

  auto compute = [&](const char* base) {
    short8 aF[4], bF[4];
    if constexpr (A_F32) {
      #pragma unroll
      for (int i = 0; i < 4; ++i) {
        float4 x = *(const float4*)(base + aoff[i]);          // k=q8..q8+3
        float4 y = *(const float4*)(base + (aoff[i] ^ 16));   // k=q8+4..q8+7
        const u32* xb = (const u32*)&x;
        const u32* yb = (const u32*)&y;
        union { u32 w[4]; short8 s; } cv;
        cv.w[0] = __builtin_amdgcn_perm(xb[1], xb[0], 0x07060302u);  // trunc pack
        cv.w[1] = __builtin_amdgcn_perm(xb[3], xb[2], 0x07060302u);
        cv.w[2] = __builtin_amdgcn_perm(yb[1], yb[0], 0x07060302u);
        cv.w[3] = __builtin_amdgcn_perm(yb[3], yb[2], 0x07060302u);
        aF[i] = cv.s;
      }
    } else {
      #pragma unroll
      for (int i = 0; i < 4; ++i) aF[i] = *(const short8*)(base + aoff[i]);
    }
    #pragma unroll
    for (int i = 0; i < 4; ++i) bF[i] = *(const short8*)(base + ABYTES + boff[i]);
    #pragma unroll
    for (int mi = 0; mi < 4; ++mi)
      #pragma unroll
      for (int ni = 0; ni < 4; ++ni)
        acc[mi][ni] = __builtin_amdgcn_mfma_f32_16x16x32_bf16(aF[mi], bF[ni], acc[mi][ni], 0, 0, 0);
  };

  const int NIT = K >> 5;                 // always even here (K multiple of 64)
  stage(0, smem);
  for (int it = 0; it < NIT; it += 2) {
    __syncthreads();                      // drains buf0 loads; prev buf1 reads done
    if (it + 1 < NIT) stage((it + 1) * 32, smem + STRIDE);
    compute(smem);
    __syncthreads();                      // drains buf1 loads; buf0 reads done
    if (it + 2 < NIT) stage((it + 2) * 32, smem);
    compute(smem + STRIDE);
  }

  if constexpr (!TRANS_OUT) {
    #pragma unroll
    for (int mi = 0; mi < 4; ++mi) {
      #pragma unroll
      for (int ni = 0; ni < 4; ++ni) {
        int col = bn0 + wn * 64 + ni * 16 + fl;
        #pragma unroll
        for (int r = 0; r < 4; ++r) {
          int row = bm0 + wm * 64 + mi * 16 + r4 + r;
          float vv = acc[mi][ni][r];
          if constexpr (EPI == EPI_PHI_BIAS) { vv += bias[col]; vv = __expf(-0.5f * vv * vv); }
          if constexpr (EPI == EPI_BIAS || EPI == EPI_BIAS_F32) vv += bias[col];
          if constexpr (EPI == EPI_ZSCALE) vv *= Zall[(size_t)abz * sZb + row];
          if constexpr (EPI == EPI_BIAS_F32)
            ((float*)Call)[(size_t)bz * sCb + (size_t)row * ldC + col] = vv;
          else
            ((u16*)Call)[(size_t)bz * sCb + (size_t)row * ldC + col] = f2b(vv);
        }
      }
    }
  } else {
    // transpose tile through LDS, then coalesced 16B stores into [4][N][4096]
    __syncthreads();
    u16* sT = (u16*)smem;  // [128][136] = 34816 B, fits in 2*STRIDE for A_F32
    #pragma unroll
    for (int mi = 0; mi < 4; ++mi) {
      #pragma unroll
      for (int ni = 0; ni < 4; ++ni) {
        int colL = wn * 64 + ni * 16 + fl;
        int row0 = wm * 64 + mi * 16 + r4;
        float bcol = bias[bn0 + colL];
        ushort4 h;
        #pragma unroll
        for (int r = 0; r < 4; ++r) {
          float vv = acc[mi][ni][r] + bcol;
          if constexpr (EPI == EPI_PHI_BIAS) vv = __expf(-0.5f * vv * vv);
          ((u16*)&h)[r] = f2b(vv);
        }
        *(ushort4*)(sT + colL * 136 + row0) = h;
      }
    }
    __syncthreads();
    #pragma unroll
    for (int i = 0; i < 8; ++i) {
      int c = tid + i * 256;                // 2048 x 16B chunks
      int dloc = c >> 4, t8 = (c & 15) * 8;
      int4 vv = *(const int4*)(sT + dloc * 136 + t8);
      int gd = bn0 + dloc;
      int gt = bm0 + t8;
      int batch = gt >> 12, tt = gt & 4095;
      *(int4*)((u16*)Call + ((size_t)batch * N + gd) * 4096 + tt) = vv;
    }
  }
}

__global__ __launch_bounds__(256)
void wconv(const float* __restrict__ w0, const float* __restrict__ w1,
           const float* __restrict__ w2, const float* __restrict__ w3,
           u16* __restrict__ dst) {
  unsigned e = blockIdx.x * 256 + threadIdx.x;
  int mat = e >> 18;
  size_t off = (size_t)(e & 262143) * 4;
  const float* src = mat == 0 ? w0 : mat == 1 ? w1 : mat == 2 ? w2 : w3;
  float4 v = *(const float4*)(src + off);
  ushort4 h;
  h.x = f2b(v.x); h.y = f2b(v.y); h.z = f2b(v.z); h.w = f2b(v.w);
  *(ushort4*)(dst + (size_t)mat * 1048576 + off) = h;
}

// KVT[i] = round(sum over 4 K-slices of bf16 partials), i over 4M elements
__global__ __launch_bounds__(256)
void reduceKV(const u16* __restrict__ P, u16* __restrict__ KVT) {
  size_t i = ((size_t)blockIdx.x * 256 + threadIdx.x) * 8;
  int4 a = *(const int4*)(P + i);
  int4 b = *(const int4*)(P + i + 4194304);
  int4 c = *(const int4*)(P + i + 8388608);
  int4 d = *(const int4*)(P + i + 12582912);
  const u16* ha = (const u16*)&a; const u16* hb = (const u16*)&b;
  const u16* hc = (const u16*)&c; const u16* hd = (const u16*)&d;
  ushort4 o0, o1;
  #pragma unroll
  for (int j = 0; j < 8; ++j) {
    float s = b2f(ha[j]) + b2f(hb[j]) + b2f(hc[j]) + b2f(hd[j]);
    ((u16*)(j < 4 ? &o0 : &o1))[j & 3] = f2b(s);
  }
  *(ushort4*)(KVT + i) = o0;
  *(ushort4*)(KVT + i + 4) = o1;
}

// Ksum[b*1024+d] = sum_t KT[b][d][t]; one wave per (b,d) row
__global__ __launch_bounds__(256)
void ksum_rows(const u16* __restrict__ KT, float* __restrict__ Ksum) {
  int lane = threadIdx.x & 63;
  int row = blockIdx.x * 4 + (threadIdx.x >> 6);
  const u16* p = KT + (size_t)row * 4096;
  float s = 0.f;
  #pragma unroll
  for (int i = 0; i < 8; ++i) {
    int4 d = *(const int4*)(p + i * 512 + lane * 8);
    const u16* h = (const u16*)&d;
    #pragma unroll
    for (int j = 0; j < 8; ++j) s += b2f(h[j]);
  }
  #pragma unroll
  for (int off = 32; off; off >>= 1) s += __shfl_xor(s, off, 64);
  if (lane == 0) Ksum[row] = s;
}

// Z[t] = 1/(Q[t,:]·Ksum[batch,:] + 1e-6); one wave per token
__global__ __launch_bounds__(256)
void zden(const u16* __restrict__ Qb, const float* __restrict__ Ksum,
          float* __restrict__ Z) {
  int lane = threadIdx.x & 63;
  int t = blockIdx.x * 4 + (threadIdx.x >> 6);
  const u16* qp = Qb + (size_t)t * 1024;
  const float* ks = Ksum + (size_t)(t >> 12) * 1024;
  float s = 0.f;
  #pragma unroll
  for (int i = 0; i < 2; ++i) {
    int idx = i * 512 + lane * 8;
    int4 d = *(const int4*)(qp + idx);
    const u16* h = (const u16*)&d;
    float4 k0 = *(const float4*)(ks + idx);
    float4 k1 = *(const float4*)(ks + idx + 4);
    s += b2f(h[0]) * k0.x + b2f(h[1]) * k0.y + b2f(h[2]) * k0.z + b2f(h[3]) * k0.w
       + b2f(h[4]) * k1.x + b2f(h[5]) * k1.y + b2f(h[6]) * k1.z + b2f(h[7]) * k1.w;
  }
  #pragma unroll
  for (int off = 32; off; off >>= 1) s += __shfl_xor(s, off, 64);
  if (lane == 0) Z[t] = 1.0f / (s + 1e-6f);
}

extern "C" void kernel_launch(void* const* d_in, const int* in_sizes, int n_in,
                              void* d_out, int out_size, void* d_ws, size_t ws_size,
                              hipStream_t stream) {
  const float* q  = (const float*)d_in[0];
  const float* k  = (const float*)d_in[1];
  const float* v  = (const float*)d_in[2];
  const float* Wq = (const float*)d_in[3];
  const float* bq = (const float*)d_in[4];
  const float* Wk = (const float*)d_in[5];
  const float* bk = (const float*)d_in[6];
  const float* Wv = (const float*)d_in[7];
  const float* bv = (const float*)d_in[8];
  const float* Wo = (const float*)d_in[9];
  const float* bo = (const float*)d_in[10];
  float* out = (float*)d_out;

  // workspace layout (~112.1 MiB)
  u16* Wqb = (u16*)d_ws;                 // 4x 1024x1024 bf16 = 8 MiB
  u16* Wkb = Wqb + 1048576;
  u16* Wvb = Wkb + 1048576;
  u16* Wob = Wvb + 1048576;
  u16* Qb  = Wob + 1048576;              // [16384][1024] bf16, 32 MiB
  u16* KT  = Qb  + 16777216;             // [4][1024][4096] bf16, 32 MiB
  u16* VT  = KT  + 16777216;             // [4][1024][4096] bf16, 32 MiB
  u16* KVT = VT  + 16777216;             // [4][1024][1024] bf16, 8 MiB
  float* Ksum = (float*)(KVT + 4194304); // [4][1024] f32
  float* Z    = Ksum + 4096;             // [16384] f32
  u16* Y = KT;                           // alias: KT dead after S2
  u16* Pkv = Qb;                         // alias: split-K partials live in Qb
                                         // region BEFORE the Q projection runs

  wconv<<<4096, 256, 0, stream>>>(Wq, Wk, Wv, Wo, Wqb);

  // K,V projections first (A fp32, in-register trunc->bf16), transposed out.
  dim3 g1(128, 8, 1);
  gemm_bt<EPI_PHI_BIAS, true, true><<<g1, 256, 0, stream>>>(
      k, Wkb, bk, nullptr, KT, 16384, 1024, 1024, 1024, 1024, 0, 0, 0, 0, 0, 0, 30);
  gemm_bt<EPI_BIAS, true, true><<<g1, 256, 0, stream>>>(
      v, Wvb, bv, nullptr, VT, 16384, 1024, 1024, 1024, 1024, 0, 0, 0, 0, 0, 0, 30);

  ksum_rows<<<1024, 256, 0, stream>>>(KT, Ksum);

  // S2: split-K x4. z = kslice*4+batch; partials P[kslice][batch][l][d] bf16.
  dim3 g2(8, 8, 16);
  gemm_bt<EPI_NONE, false, false><<<g2, 256, 0, stream>>>(
      VT, KT, nullptr, nullptr, Pkv, 1024, 1024, 1024, 4096, 4096, 1024,
      4194304L, 4194304L, 1048576L, 0, 3, 2);
  reduceKV<<<2048, 256, 0, stream>>>(Pkv, KVT);

  // Q projection (overwrites the partials region — stream-ordered after reduce)
  gemm_bt<EPI_PHI_BIAS, true, false><<<g1, 256, 0, stream>>>(
      q, Wqb, bq, nullptr, Qb, 16384, 1024, 1024, 1024, 1024, 1024, 0, 0, 0, 0, 0, 30);

  zden<<<4096, 256, 0, stream>>>(Qb, Ksum, Z);

  // S3: Y[t,l] = (sum_d Qb[t,d] * KVT[l,d]) * Z[t]  (per batch)
  dim3 g3(32, 8, 4);
  gemm_bt<EPI_ZSCALE, false, false><<<g3, 256, 0, stream>>>(
      Qb, KVT, nullptr, Z, Y, 4096, 1024, 1024, 1024, 1024, 1024,
      4194304L, 1048576L, 4194304L, 4096L, 3, 30);

  // S4: out[t,n] = sum_l Y[t,l] * Wo[n,l] + bo[n]  (fp32 out)
  dim3 g4(128, 8, 1);
  gemm_bt<EPI_BIAS_F32, false, false><<<g4, 256, 0, stream>>>(
      Y, Wob, bo, nullptr, out, 16384, 1024, 1024, 1024, 1024, 1024, 0, 0, 0, 0, 0, 30);
}

// Round 4
// 544.479 us; speedup vs baseline: 1.2442x; 1.0627x over previous
//
#include <hip/hip_runtime.h>

typedef unsigned short u16;
typedef unsigned int u32;
typedef unsigned long long u64;

typedef __attribute__((ext_vector_type(8))) short short8;   // 8 bf16 = 4 VGPRs
typedef __attribute__((ext_vector_type(4))) float floatx4;  // MFMA accumulator

__device__ __forceinline__ float b2f(u16 h) {
  u32 u = ((u32)h) << 16;
  return __builtin_bit_cast(float, u);
}
__device__ __forceinline__ u16 f2b(float f) {
  u32 u = __builtin_bit_cast(u32, f);
  u32 r = 0x7FFFu + ((u >> 16) & 1u);  // RNE
  return (u16)((u + r) >> 16);
}

// async global->LDS, 16B per lane. LDS dest = wave-uniform base + lane*16.
__device__ __forceinline__ void gl_lds16(const void* g, void* l) {
  __builtin_amdgcn_global_load_lds(
      (__attribute__((address_space(1))) void*)(u64)g,
      (__attribute__((address_space(3))) void*)(u32)(u64)l, 16, 0, 0);
}

enum { EPI_PHI_BIAS = 0, EPI_BIAS = 1, EPI_NONE = 2, EPI_ZSCALE = 3,
       EPI_BIAS_F32 = 4, EPI_ZBIAS_F32 = 5 };

// C[m,n] = sum_k A[m,k] * B[n,k]  (both K-contiguous). 128x128x32 tile, 4 waves.
// Double-buffered LDS; prefetch for tile k+1 issued AFTER the barrier draining
// tile k, overlapping tile k's ds_read+MFMA phase.
// bf16 tiles in LDS: superrow XOR swizzle (R=r>>1, u=((r&1)<<2)|c, phys=R*8+(u^(R&7))).
// fp32 A tile: TWO 8KB k-halves (k 0..15 / 16..31), each 128 rows x 4 chunks with
// the same superrow swizzle -> fragment float4 reads hit all 8 bank-groups evenly.
// Split-K: blockIdx.z = kslice*(abmask+1)+batch; abz=bz&abmask, kbase=(bz>>kshift)*K.
// DUAL: bz selects operand set 1 (A2/B2/bias2/C2, no phi) vs set 0 (phi).
template<int EPI, bool A_F32, bool TRANS_OUT, bool DUAL>
__global__ __launch_bounds__(256)
void gemm_bt(const void* __restrict__ Aall, const u16* __restrict__ Ball,
             const float* __restrict__ bias, const float* __restrict__ Zall,
             void* __restrict__ Call,
             int M, int N, int K, int ldA, int ldB, int ldC,
             long sAb, long sBb, long sCb, long sZb, int abmask, int kshift,
             const void* __restrict__ Aall2, const u16* __restrict__ Ball2,
             const float* __restrict__ bias2, void* __restrict__ Call2)
{
  constexpr int ABYTES = A_F32 ? 16384 : 8192;
  constexpr int STRIDE = ABYTES + 8192;           // one stage buffer (A+B)
  constexpr int SMEM   = (TRANS_OUT && 34816 > 2 * STRIDE) ? 34816 : 2 * STRIDE;
  __shared__ char smem[SMEM];

  const int tid  = threadIdx.x;
  const int lane = tid & 63;
  const int wave = tid >> 6;
  const int wm = wave >> 1, wn = wave & 1;   // 2x2 waves, 64x64 each
  const int fl = lane & 15;
  const int q  = lane >> 4;
  const int r4 = q * 4;
  const int bm0 = blockIdx.x * 128, bn0 = blockIdx.y * 128;
  const int bz = blockIdx.z;
  const int abz = bz & abmask;
  const int kbase = (bz >> kshift) * K;

  const void* Asel = Aall; const u16* Bsel = Ball;
  const float* biasSel = bias; void* Csel = Call;
  bool phi_on = true;
  if constexpr (DUAL) {
    if (bz) { Asel = Aall2; Bsel = Ball2; biasSel = bias2; Csel = Call2; phi_on = false; }
  }

  const float* Af = (const float*)Asel + (size_t)abz * sAb + kbase;
  const u16*   Ah = (const u16*)Asel + (size_t)abz * sAb + kbase;
  const u16*   Bp = Bsel + (size_t)abz * sBb + kbase;

  // ---- staging addresses (global per-lane; LDS offsets wave-uniform) ----
  const u16* gB[2]; int bL[2];
  #pragma unroll
  for (int n = 0; n < 2; ++n) {
    int j = n * 256 + tid;                 // physical 16B slot in B tile
    int R = j >> 3, u = (j & 7) ^ (R & 7);
    int r = (R << 1) | (u >> 2), c = u & 3;
    gB[n] = Bp + (size_t)(bn0 + r) * ldB + c * 8;
    bL[n] = (n * 256 + wave * 64) * 16;
  }
  const u16* gAh[2]; const float* gAf[4]; int aL[4];
  if constexpr (A_F32) {
    #pragma unroll
    for (int n = 0; n < 4; ++n) {
      int sl = n * 256 + tid;              // 0..1023 over two 512-slot halves
      int h = sl >> 9, s = sl & 511;
      int R = s >> 3, u = (s & 7) ^ (R & 7);
      int r = (R << 1) | (u >> 2), c4 = u & 3;
      gAf[n] = Af + (size_t)(bm0 + r) * ldA + h * 16 + c4 * 4;
      aL[n] = (n * 256 + wave * 64) * 16;
    }
  } else {
    #pragma unroll
    for (int n = 0; n < 2; ++n) {
      int j = n * 256 + tid;
      int R = j >> 3, u = (j & 7) ^ (R & 7);
      int r = (R << 1) | (u >> 2), c = u & 3;
      gAh[n] = Ah + (size_t)(bm0 + r) * ldA + c * 8;
      aL[n] = (n * 256 + wave * 64) * 16;
    }
  }

  // ---- fragment LDS byte offsets (within one stage buffer) ----
  int aoff[4], boff[4];
  #pragma unroll
  for (int i = 0; i < 4; ++i) {
    int rb = wn * 64 + i * 16 + fl;
    int Rb = rb >> 1, ub = ((((rb & 1) << 2) | q) ^ (Rb & 7));
    boff[i] = (Rb * 8 + ub) * 16;
    int ra = wm * 64 + i * 16 + fl;
    if constexpr (A_F32) {
      int hq = q >> 1, c4x = (q & 1) * 2;        // x: k=8q..8q+3, y = x^16
      int Ra = ra >> 1;
      int ux = ((((ra & 1) << 2) | c4x) ^ (Ra & 7));
      aoff[i] = hq * 8192 + (Ra * 8 + ux) * 16;
    } else {
      int Ra = ra >> 1, ua = ((((ra & 1) << 2) | q) ^ (Ra & 7));
      aoff[i] = (Ra * 8 + ua) * 16;
    }
  }

  floatx4 zero = {0.f, 0.f, 0.f, 0.f};
  floatx4 acc[4][4];
  #pragma unroll
  for (int i = 0; i < 4; ++i)
    #pragma unroll
    for (int j = 0; j < 4; ++j) acc[i][j] = zero;

  auto stage = [&](int k0, char* base) {
    if constexpr (A_F32) {
      #pragma unroll
      for (int n = 0; n < 4; ++n) gl_lds16(gAf[n] + k0, base + aL[n]);
    } else {
      #pragma unroll
      for (int n = 0; n < 2; ++n) gl_lds16(gAh[n] + k0, base + aL[n]);
    }
    #pragma unroll
    for (int n = 0; n < 2; ++n) gl_lds16(gB[n] + k0, base + ABYTES + bL[n]);
  };

  auto compute = [&](const char* base) {
    short8 aF[4], bF[4];
    if constexpr (A_F32) {
      #pragma unroll
      for (int i = 0; i < 4; ++i) {
        float4 x = *(const float4*)(base + aoff[i]);          // k=8q..8q+3
        float4 y = *(const float4*)(base + (aoff[i] ^ 16));   // k=8q+4..8q+7
        const u32* xb = (const u32*)&x;
        const u32* yb = (const u32*)&y;
        union { u32 w[4]; short8 s; } cv;
        cv.w[0] = __builtin_amdgcn_perm(xb[1], xb[0], 0x07060302u);  // trunc pack
        cv.w[1] = __builtin_amdgcn_perm(xb[3], xb[2], 0x07060302u);
        cv.w[2] = __builtin_amdgcn_perm(yb[1], yb[0], 0x07060302u);
        cv.w[3] = __builtin_amdgcn_perm(yb[3], yb[2], 0x07060302u);
        aF[i] = cv.s;
      }
    } else {
      #pragma unroll
      for (int i = 0; i < 4; ++i) aF[i] = *(const short8*)(base + aoff[i]);
    }
    #pragma unroll
    for (int i = 0; i < 4; ++i) bF[i] = *(const short8*)(base + ABYTES + boff[i]);
    #pragma unroll
    for (int mi = 0; mi < 4; ++mi)
      #pragma unroll
      for (int ni = 0; ni < 4; ++ni)
        acc[mi][ni] = __builtin_amdgcn_mfma_f32_16x16x32_bf16(aF[mi], bF[ni], acc[mi][ni], 0, 0, 0);
  };

  const int NIT = K >> 5;                 // even for all our shapes
  stage(0, smem);
  for (int it = 0; it < NIT; it += 2) {
    __syncthreads();                      // drains buf0 loads; prev buf1 reads done
    if (it + 1 < NIT) stage((it + 1) * 32, smem + STRIDE);
    compute(smem);
    __syncthreads();                      // drains buf1 loads; buf0 reads done
    if (it + 2 < NIT) stage((it + 2) * 32, smem);
    compute(smem + STRIDE);
  }

  if constexpr (!TRANS_OUT) {
    #pragma unroll
    for (int mi = 0; mi < 4; ++mi) {
      #pragma unroll
      for (int ni = 0; ni < 4; ++ni) {
        int col = bn0 + wn * 64 + ni * 16 + fl;
        #pragma unroll
        for (int r = 0; r < 4; ++r) {
          int row = bm0 + wm * 64 + mi * 16 + r4 + r;
          float vv = acc[mi][ni][r];
          if constexpr (EPI == EPI_PHI_BIAS) {
            vv += biasSel[col];
            if (phi_on) vv = __expf(-0.5f * vv * vv);
          }
          if constexpr (EPI == EPI_BIAS || EPI == EPI_BIAS_F32) vv += biasSel[col];
          if constexpr (EPI == EPI_ZSCALE) vv *= Zall[(size_t)abz * sZb + row];
          if constexpr (EPI == EPI_ZBIAS_F32)
            vv = vv * Zall[(size_t)abz * sZb + row] + biasSel[col];
          if constexpr (EPI == EPI_BIAS_F32 || EPI == EPI_ZBIAS_F32)
            ((float*)Csel)[(size_t)bz * sCb + (size_t)row * ldC + col] = vv;
          else
            ((u16*)Csel)[(size_t)bz * sCb + (size_t)row * ldC + col] = f2b(vv);
        }
      }
    }
  } else {
    // transpose tile through LDS, then coalesced 16B stores into [4][N][4096]
    __syncthreads();
    u16* sT = (u16*)smem;  // [128][136] = 34816 B
    #pragma unroll
    for (int mi = 0; mi < 4; ++mi) {
      #pragma unroll
      for (int ni = 0; ni < 4; ++ni) {
        int colL = wn * 64 + ni * 16 + fl;
        int row0 = wm * 64 + mi * 16 + r4;
        float bcol = biasSel[bn0 + colL];
        ushort4 h;
        #pragma unroll
        for (int r = 0; r < 4; ++r) {
          float vv = acc[mi][ni][r] + bcol;
          if (phi_on) vv = __expf(-0.5f * vv * vv);
          ((u16*)&h)[r] = f2b(vv);
        }
        *(ushort4*)(sT + colL * 136 + row0) = h;
      }
    }
    __syncthreads();
    #pragma unroll
    for (int i = 0; i < 8; ++i) {
      int c = tid + i * 256;                // 2048 x 16B chunks
      int dloc = c >> 4, t8 = (c & 15) * 8;
      int4 vv = *(const int4*)(sT + dloc * 136 + t8);
      int gd = bn0 + dloc;
      int gt = bm0 + t8;
      int batch = gt >> 12, tt = gt & 4095;
      *(int4*)((u16*)Csel + ((size_t)batch * N + gd) * 4096 + tt) = vv;
    }
  }
}

__global__ __launch_bounds__(256)
void wconv(const float* __restrict__ w0, const float* __restrict__ w1,
           const float* __restrict__ w2, const float* __restrict__ w3,
           u16* __restrict__ dst) {
  unsigned e = blockIdx.x * 256 + threadIdx.x;
  int mat = e >> 18;
  size_t off = (size_t)(e & 262143) * 4;
  const float* src = mat == 0 ? w0 : mat == 1 ? w1 : mat == 2 ? w2 : w3;
  float4 v = *(const float4*)(src + off);
  ushort4 h;
  h.x = f2b(v.x); h.y = f2b(v.y); h.z = f2b(v.z); h.w = f2b(v.w);
  *(ushort4*)(dst + (size_t)mat * 1048576 + off) = h;
}

// out[i] = round(sum over 4 K-slices of bf16 partials), 4M elems, slice stride 4M
__global__ __launch_bounds__(256)
void reduce4(const u16* __restrict__ P, u16* __restrict__ out) {
  size_t i = ((size_t)blockIdx.x * 256 + threadIdx.x) * 8;
  int4 a = *(const int4*)(P + i);
  int4 b = *(const int4*)(P + i + 4194304);
  int4 c = *(const int4*)(P + i + 8388608);
  int4 d = *(const int4*)(P + i + 12582912);
  const u16* ha = (const u16*)&a; const u16* hb = (const u16*)&b;
  const u16* hc = (const u16*)&c; const u16* hd = (const u16*)&d;
  ushort4 o0, o1;
  #pragma unroll
  for (int j = 0; j < 8; ++j) {
    float s = b2f(ha[j]) + b2f(hb[j]) + b2f(hc[j]) + b2f(hd[j]);
    ((u16*)(j < 4 ? &o0 : &o1))[j & 3] = f2b(s);
  }
  *(ushort4*)(out + i) = o0;
  *(ushort4*)(out + i + 4) = o1;
}

// Ksum[b*1024+d] = sum_t KT[b][d][t]; one wave per (b,d) row
__global__ __launch_bounds__(256)
void ksum_rows(const u16* __restrict__ KT, float* __restrict__ Ksum) {
  int lane = threadIdx.x & 63;
  int row = blockIdx.x * 4 + (threadIdx.x >> 6);
  const u16* p = KT + (size_t)row * 4096;
  float s = 0.f;
  #pragma unroll
  for (int i = 0; i < 8; ++i) {
    int4 d = *(const int4*)(p + i * 512 + lane * 8);
    const u16* h = (const u16*)&d;
    #pragma unroll
    for (int j = 0; j < 8; ++j) s += b2f(h[j]);
  }
  #pragma unroll
  for (int off = 32; off; off >>= 1) s += __shfl_xor(s, off, 64);
  if (lane == 0) Ksum[row] = s;
}

// Z[t] = 1/(Q[t,:]·Ksum[batch,:] + 1e-6); one wave per token
__global__ __launch_bounds__(256)
void zden(const u16* __restrict__ Qb, const float* __restrict__ Ksum,
          float* __restrict__ Z) {
  int lane = threadIdx.x & 63;
  int t = blockIdx.x * 4 + (threadIdx.x >> 6);
  const u16* qp = Qb + (size_t)t * 1024;
  const float* ks = Ksum + (size_t)(t >> 12) * 1024;
  float s = 0.f;
  #pragma unroll
  for (int i = 0; i < 2; ++i) {
    int idx = i * 512 + lane * 8;
    int4 d = *(const int4*)(qp + idx);
    const u16* h = (const u16*)&d;
    float4 k0 = *(const float4*)(ks + idx);
    float4 k1 = *(const float4*)(ks + idx + 4);
    s += b2f(h[0]) * k0.x + b2f(h[1]) * k0.y + b2f(h[2]) * k0.z + b2f(h[3]) * k0.w
       + b2f(h[4]) * k1.x + b2f(h[5]) * k1.y + b2f(h[6]) * k1.z + b2f(h[7]) * k1.w;
  }
  #pragma unroll
  for (int off = 32; off; off >>= 1) s += __shfl_xor(s, off, 64);
  if (lane == 0) Z[t] = 1.0f / (s + 1e-6f);
}

extern "C" void kernel_launch(void* const* d_in, const int* in_sizes, int n_in,
                              void* d_out, int out_size, void* d_ws, size_t ws_size,
                              hipStream_t stream) {
  const float* q  = (const float*)d_in[0];
  const float* k  = (const float*)d_in[1];
  const float* v  = (const float*)d_in[2];
  const float* Wq = (const float*)d_in[3];
  const float* bq = (const float*)d_in[4];
  const float* Wk = (const float*)d_in[5];
  const float* bk = (const float*)d_in[6];
  const float* Wv = (const float*)d_in[7];
  const float* bv = (const float*)d_in[8];
  const float* Wo = (const float*)d_in[9];
  const float* bo = (const float*)d_in[10];
  float* out = (float*)d_out;

  // workspace layout (~112.1 MiB) with aliasing:
  u16* Wqb = (u16*)d_ws;                 // 4x 1024x1024 bf16 = 8 MiB
  u16* Wkb = Wqb + 1048576;
  u16* Wvb = Wkb + 1048576;
  u16* Wob = Wvb + 1048576;
  u16* Qb  = Wob + 1048576;              // [16384][1024] bf16, 32 MiB
  u16* KT  = Qb  + 16777216;             // [4][1024][4096] bf16, 32 MiB
  u16* VT  = KT  + 16777216;             // [4][1024][4096] bf16, 32 MiB
  u16* KVr = VT  + 16777216;             // [4][1024(d)][1024(l)] bf16, 8 MiB
  float* Ksum = (float*)(KVr + 4194304); // [4][1024] f32
  float* Z    = Ksum + 4096;             // [16384] f32
  u16* Pkv = Qb;   // S2 split-K partials, before Q-proj overwrites
  u16* Pg  = VT;   // G split-K partials, after VT dead
  u16* Gp  = KT;   // G' [4][1024(n)][1024(d)], after KT dead

  wconv<<<4096, 256, 0, stream>>>(Wq, Wk, Wv, Wo, Wqb);

  // K,V projections in ONE dispatch (grid z: 0=K with phi, 1=V bias-only).
  dim3 gkv(128, 8, 2);
  gemm_bt<EPI_PHI_BIAS, true, true, true><<<gkv, 256, 0, stream>>>(
      k, Wkb, bk, nullptr, KT, 16384, 1024, 1024, 1024, 1024, 0,
      0, 0, 0, 0, 0, 30, v, Wvb, bv, VT);

  ksum_rows<<<1024, 256, 0, stream>>>(KT, Ksum);

  // S2: KVr[d,l] = sum_t KT[d,t]*VT[l,t], split-K x4 (z = kslice*4+batch)
  dim3 g2(8, 8, 16);
  gemm_bt<EPI_NONE, false, false, false><<<g2, 256, 0, stream>>>(
      KT, VT, nullptr, nullptr, Pkv, 1024, 1024, 1024, 4096, 4096, 1024,
      4194304L, 4194304L, 1048576L, 0, 3, 2, nullptr, nullptr, nullptr, nullptr);
  reduce4<<<2048, 256, 0, stream>>>(Pkv, KVr);

  // Q projection (overwrites partials region — stream-ordered after reduce)
  dim3 g1(128, 8, 1);
  gemm_bt<EPI_PHI_BIAS, true, false, false><<<g1, 256, 0, stream>>>(
      q, Wqb, bq, nullptr, Qb, 16384, 1024, 1024, 1024, 1024, 1024,
      0, 0, 0, 0, 0, 30, nullptr, nullptr, nullptr, nullptr);

  zden<<<4096, 256, 0, stream>>>(Qb, Ksum, Z);

  // G'[n,d] = sum_l Wob[n,l]*KVr[d,l], split-K x4 (K=256/slice); Wo folded in.
  dim3 gg(8, 8, 16);
  gemm_bt<EPI_NONE, false, false, false><<<gg, 256, 0, stream>>>(
      Wob, KVr, nullptr, nullptr, Pg, 1024, 1024, 256, 1024, 1024, 1024,
      0L, 1048576L, 1048576L, 0, 3, 2, nullptr, nullptr, nullptr, nullptr);
  reduce4<<<2048, 256, 0, stream>>>(Pg, Gp);

  // final: out[t,n] = Z[t]*(sum_d Qb[t,d]*G'[n,d]) + bo[n], fp32 out
  dim3 gf(32, 8, 4);
  gemm_bt<EPI_ZBIAS_F32, false, false, false><<<gf, 256, 0, stream>>>(
      Qb, Gp, bo, Z, out, 4096, 1024, 1024, 1024, 1024, 1024,
      4194304L, 1048576L, 4194304L, 4096L, 3, 30, nullptr, nullptr, nullptr, nullptr);
}